// Round 1
// baseline (633.276 us; speedup 1.0000x reference)
//
#include <hip/hip_runtime.h>
#include <math.h>

// SoftGate: gate-MLP -> threshold -> stable compaction.
// Shapes fixed by the reference setup (verified against in_sizes):
#define NB 8
#define NS 4096
#define ND 1024
#define NDH 512
#define NTOK (NB * NS)
#define THRESH 0.1f
#define EPSV 1e-5f
#define KC 16

// ---------------------------------------------------------------------------
// K1: y_lin[token] = sum_h relu(x[token]·W1[:,h] + b1[h]) * W2[h]
// fp32 vector GEMM, M-tile=32 tokens x full N=512, K staged in LDS (KC=16).
// Deterministic (fixed-order FMA + shfl_xor butterfly) — no atomics, so the
// near-threshold mask decisions are identical across graph replays.
// ---------------------------------------------------------------------------
__global__ __launch_bounds__(256, 2)
void k1_gemm(const float* __restrict__ x, const float* __restrict__ W1,
             const float* __restrict__ b1, const float* __restrict__ W2,
             float* __restrict__ ylin) {
  __shared__ float sx[KC][36];    // x tile, transposed [k][tok], padded for b128 align
  __shared__ float sw[KC][516];   // W1 tile [k][col], padded (516*4 % 16 == 0)

  const int tid = threadIdx.x;
  const int tx = tid & 31;        // 32 col-groups (4 cols each, x4 quads = 16 cols/thread)
  const int ty = tid >> 5;        // 8 token-groups (4 tokens each)
  const int tok0 = blockIdx.x * 32;

  float acc[4][16];
#pragma unroll
  for (int t = 0; t < 4; ++t)
#pragma unroll
    for (int j = 0; j < 16; ++j) acc[t][j] = 0.f;

  const int lt = tid >> 3;        // staging: token 0..31
  const int lk = (tid & 7) * 2;   // staging: even k 0..14

  for (int kb = 0; kb < ND; kb += KC) {
    __syncthreads();
    // stage x tile (transpose on the fly); float2 per thread
    float2 xv = *(const float2*)(x + (size_t)(tok0 + lt) * ND + kb + lk);
    sx[lk][lt] = xv.x;
    sx[lk + 1][lt] = xv.y;
    // stage W1 tile: 16 rows x 512 cols = 2048 float4 / 256 threads = 8 each
#pragma unroll
    for (int i = 0; i < 8; ++i) {
      int f = i * 256 + tid;
      int k = f >> 7;
      int c4 = (f & 127) << 2;
      *(float4*)&sw[k][c4] = *(const float4*)(W1 + (size_t)(kb + k) * NDH + c4);
    }
    __syncthreads();
#pragma unroll
    for (int k = 0; k < KC; ++k) {
      float4 a = *(const float4*)&sx[k][ty * 4];
      float av[4] = {a.x, a.y, a.z, a.w};
#pragma unroll
      for (int q = 0; q < 4; ++q) {
        float4 w = *(const float4*)&sw[k][tx * 4 + q * 128];
        float wv[4] = {w.x, w.y, w.z, w.w};
#pragma unroll
        for (int t = 0; t < 4; ++t)
#pragma unroll
          for (int j = 0; j < 4; ++j)
            acc[t][q * 4 + j] = fmaf(av[t], wv[j], acc[t][q * 4 + j]);
      }
    }
  }

  // epilogue: relu + b1, dot with W2 -> per-thread partial y_lin for 4 tokens
  float part[4] = {0.f, 0.f, 0.f, 0.f};
#pragma unroll
  for (int q = 0; q < 4; ++q) {
#pragma unroll
    for (int j = 0; j < 4; ++j) {
      int c = tx * 4 + q * 128 + j;
      float bb = b1[c];
      float w2 = W2[c];
#pragma unroll
      for (int t = 0; t < 4; ++t) {
        float h = fmaxf(acc[t][q * 4 + j] + bb, 0.f);
        part[t] = fmaf(h, w2, part[t]);
      }
    }
  }
  // reduce over the 32 col-group lanes (tx) within each half-wave: masks <32
  // stay inside the 32-lane half, so each half reduces its own token group.
#pragma unroll
  for (int m = 16; m >= 1; m >>= 1)
#pragma unroll
    for (int t = 0; t < 4; ++t) part[t] += __shfl_xor(part[t], m, 64);
  if (tx == 0) {
#pragma unroll
    for (int t = 0; t < 4; ++t) ylin[tok0 + ty * 4 + t] = part[t];
  }
}

// ---------------------------------------------------------------------------
// K2: per batch row — squash, zero pads, row max -> adjust, threshold mask,
// stable block prefix-scan -> src_of_dest mapping, new_len, v_pad output.
// One block per row; 256 threads x 16 contiguous tokens each (stable order).
// ---------------------------------------------------------------------------
__global__ __launch_bounds__(256)
void k2_row(const float* __restrict__ ylin, const int* __restrict__ pad,
            const float* __restrict__ b2, float* __restrict__ yfin,
            int* __restrict__ src_of_dest, int* __restrict__ new_len,
            float* __restrict__ vpad_out) {
  __shared__ float sred[256];
  __shared__ int scnt[256];
  const int b = blockIdx.x;
  const int tid = threadIdx.x;
  const int base = b * NS;
  const int s0 = tid * 16;

  float yv[16];
  unsigned pm = 0;
  float lmax = 0.f;  // reference max includes the zeroed pads; y >= 0 anyway
  const float b2v = b2[0];
#pragma unroll
  for (int i = 0; i < 16; ++i) {
    int s = s0 + i;
    float yl = ylin[base + s] + b2v;
    float y = (1.f + tanhf(10.f * yl)) * 0.5f;
    if (pad[base + s]) { y = 0.f; pm |= (1u << i); }
    yv[i] = y;
    lmax = fmaxf(lmax, y);
  }
  sred[tid] = lmax;
  __syncthreads();
  for (int o = 128; o > 0; o >>= 1) {
    if (tid < o) sred[tid] = fmaxf(sred[tid], sred[tid + o]);
    __syncthreads();
  }
  const float adj = fmaxf(EPSV + THRESH - sred[0], 0.f);

  int cnt = 0;
  unsigned km = 0;
#pragma unroll
  for (int i = 0; i < 16; ++i) {
    float yf = yv[i] + adj;
    yv[i] = yf;
    bool keep = (yf > THRESH) && !((pm >> i) & 1u);
    if (keep) { km |= (1u << i); ++cnt; }
  }
  scnt[tid] = cnt;
  __syncthreads();
  // Hillis-Steele inclusive scan over per-thread counts
  for (int o = 1; o < 256; o <<= 1) {
    int add = (tid >= o) ? scnt[tid - o] : 0;
    __syncthreads();
    scnt[tid] += add;
    __syncthreads();
  }
  const int total = scnt[255];
  int off = scnt[tid] - cnt;  // exclusive offset
#pragma unroll
  for (int i = 0; i < 16; ++i) {
    int s = s0 + i;
    yfin[base + s] = yv[i];
    if ((km >> i) & 1u) { src_of_dest[base + off] = s; ++off; }
    vpad_out[base + s] = (s >= total) ? 1.f : 0.f;
  }
  if (tid == 0) new_len[b] = total;
}

// ---------------------------------------------------------------------------
// K3: one block per output slot (b, dest): v = x[src]*y_final[src] or zeros.
// 256 threads x float4 = 1024 floats, fully coalesced.
// ---------------------------------------------------------------------------
__global__ __launch_bounds__(256)
void k3_gather(const float* __restrict__ x, const float* __restrict__ yfin,
               const int* __restrict__ src_of_dest, const int* __restrict__ new_len,
               float* __restrict__ v) {
  const int slot = blockIdx.x;
  const int b = slot >> 12;          // NS = 4096
  const int dest = slot & (NS - 1);
  const int tid = threadIdx.x;
  float4* vo = (float4*)(v + (size_t)slot * ND);
  if (dest < new_len[b]) {
    const int src = src_of_dest[slot];
    const float g = yfin[b * NS + src];
    const float4* xi = (const float4*)(x + ((size_t)b * NS + src) * ND);
    float4 xv = xi[tid];
    vo[tid] = make_float4(xv.x * g, xv.y * g, xv.z * g, xv.w * g);
  } else {
    vo[tid] = make_float4(0.f, 0.f, 0.f, 0.f);
  }
}

extern "C" void kernel_launch(void* const* d_in, const int* in_sizes, int n_in,
                              void* d_out, int out_size, void* d_ws, size_t ws_size,
                              hipStream_t stream) {
  const float* x  = (const float*)d_in[0];
  const int*   pad = (const int*)d_in[1];   // bool -> int32 per harness convention
  const float* W1 = (const float*)d_in[2];
  const float* b1 = (const float*)d_in[3];
  const float* W2 = (const float*)d_in[4];
  const float* b2 = (const float*)d_in[5];

  float* v    = (float*)d_out;                       // [8,4096,1024]
  float* vpad = v + (size_t)NTOK * ND;               // [8,4096] as 0.0/1.0

  // workspace layout (~384 KB)
  float* ylin = (float*)d_ws;                        // NTOK
  float* yfin = ylin + NTOK;                         // NTOK
  int* src    = (int*)(yfin + NTOK);                 // NTOK
  int* nlen   = src + NTOK;                          // NB

  k1_gemm<<<NTOK / 32, 256, 0, stream>>>(x, W1, b1, W2, ylin);
  k2_row<<<NB, 256, 0, stream>>>(ylin, pad, b2, yfin, src, nlen, vpad);
  k3_gather<<<NTOK, 256, 0, stream>>>(x, yfin, src, nlen, v);
}

// Round 2
// 336.576 us; speedup vs baseline: 1.8815x; 1.8815x over previous
//
#include <hip/hip_runtime.h>
#include <math.h>

// SoftGate: gate-MLP (split-bf16 MFMA) -> threshold -> stable compaction.
#define NB 8
#define NS 4096
#define ND 1024      // K (feature dim)
#define NDH 512      // N (hidden dim)
#define NTOK (NB*NS) // M = 32768
#define THRESH 0.1f
#define EPSV 1e-5f
#define BM 64
#define BK 16

using short8   = __attribute__((ext_vector_type(8)))  short;
using floatx16 = __attribute__((ext_vector_type(16))) float;

__device__ __forceinline__ unsigned short f32_to_bf16_rne(float f) {
  union { float f; unsigned u; } v; v.f = f;
  unsigned r = v.u + 0x7fffu + ((v.u >> 16) & 1u);
  return (unsigned short)(r >> 16);
}
__device__ __forceinline__ float bf16_to_f32(unsigned short h) {
  union { unsigned u; float f; } v; v.u = ((unsigned)h) << 16;
  return v.f;
}

// ---------------------------------------------------------------------------
// K0: split W1 fp32 [K=1024][N=512] into bf16 hi/lo, transposed + k-chunked:
//     Wt[(k>>4)*8192 + n*16 + (k&15)]  -- so k1's staging is contiguous 16 KB.
// ---------------------------------------------------------------------------
__global__ __launch_bounds__(256)
void k0_prep(const float* __restrict__ W1, unsigned short* __restrict__ WtHi,
             unsigned short* __restrict__ WtLo) {
  __shared__ unsigned short th[32][34];
  __shared__ unsigned short tl[32][34];
  const int t  = threadIdx.x;
  const int kb = (blockIdx.x & 31) * 32;
  const int nb = (blockIdx.x >> 5) * 32;
  {
    const int k = t >> 3, n0 = (t & 7) * 4;
    float4 w = *(const float4*)(W1 + (size_t)(kb + k) * NDH + nb + n0);
    float wv[4] = {w.x, w.y, w.z, w.w};
#pragma unroll
    for (int i = 0; i < 4; ++i) {
      unsigned short h = f32_to_bf16_rne(wv[i]);
      th[k][n0 + i] = h;
      tl[k][n0 + i] = f32_to_bf16_rne(wv[i] - bf16_to_f32(h));
    }
  }
  __syncthreads();
#pragma unroll
  for (int j = 0; j < 4; ++j) {
    int flat = j * 256 + t;
    int nl = flat >> 5, kl = flat & 31;
    int k = kb + kl, n = nb + nl;
    size_t o = (size_t)(k >> 4) * (NDH * 16) + (size_t)n * 16 + (k & 15);
    WtHi[o] = th[kl][nl];
    WtLo[o] = tl[kl][nl];
  }
}

// ---------------------------------------------------------------------------
// K1: ylin[token] = sum_n relu((x·W1)[n] + b1[n]) * W2[n], via 3-term
// split-bf16 MFMA (hi·hi + lo·hi + hi·lo), fp32 accumulate -> ~fp32 accuracy.
// 64-token M-tile x full N=512; wave w owns N-cols [128w,128w+128).
// 32x32x16 bf16 MFMA; LDS rows padded to 24 ushorts (48 B) for conflicts.
// ---------------------------------------------------------------------------
__global__ __launch_bounds__(256, 2)
void k1_gemm(const float* __restrict__ x, const unsigned short* __restrict__ WtHi,
             const unsigned short* __restrict__ WtLo, const float* __restrict__ b1,
             const float* __restrict__ W2, float* __restrict__ ylin) {
  __shared__ __align__(16) unsigned short smem[27648];   // 54 KB
  unsigned short* sxh = smem;            // [64][24]
  unsigned short* sxl = smem + 1536;     // [64][24]
  unsigned short* swh = smem + 3072;     // [512][24]
  unsigned short* swl = smem + 15360;    // [512][24]

  const int tid  = threadIdx.x;
  const int wave = tid >> 6, lane = tid & 63;
  const int l31  = lane & 31, h5 = lane >> 5;
  const int tok0 = blockIdx.x * BM;

  floatx16 acc[2][4];
#pragma unroll
  for (int m = 0; m < 2; ++m)
#pragma unroll
    for (int n = 0; n < 4; ++n)
#pragma unroll
      for (int r = 0; r < 16; ++r) acc[m][n][r] = 0.f;

  for (int kb = 0; kb < ND; kb += BK) {
    __syncthreads();
    // stage x tile 64x16 fp32 -> bf16 hi/lo (thread: one row-quarter)
    {
      const int m = tid >> 2, k0 = (tid & 3) * 4;
      float4 xv = *(const float4*)(x + (size_t)(tok0 + m) * ND + kb + k0);
      float v0[4] = {xv.x, xv.y, xv.z, xv.w};
      unsigned short h[4], l[4];
#pragma unroll
      for (int i = 0; i < 4; ++i) {
        h[i] = f32_to_bf16_rne(v0[i]);
        l[i] = f32_to_bf16_rne(v0[i] - bf16_to_f32(h[i]));
      }
      uint2 hp, lp;
      hp.x = (unsigned)h[0] | ((unsigned)h[1] << 16);
      hp.y = (unsigned)h[2] | ((unsigned)h[3] << 16);
      lp.x = (unsigned)l[0] | ((unsigned)l[1] << 16);
      lp.y = (unsigned)l[2] | ((unsigned)l[3] << 16);
      *(uint2*)(sxh + m * 24 + k0) = hp;
      *(uint2*)(sxl + m * 24 + k0) = lp;
    }
    // stage W hi/lo tiles: contiguous 16 KB each (k-chunked layout from k0)
    {
      const size_t cb = (size_t)(kb >> 4) * (NDH * 16);
      const uint4* gh = (const uint4*)(WtHi + cb);
      const uint4* gl = (const uint4*)(WtLo + cb);
      uint4 a0 = gh[4 * tid + 0], a1 = gh[4 * tid + 1];
      uint4 a2 = gh[4 * tid + 2], a3 = gh[4 * tid + 3];
      uint4 c0 = gl[4 * tid + 0], c1 = gl[4 * tid + 1];
      uint4 c2 = gl[4 * tid + 2], c3 = gl[4 * tid + 3];
      *(uint4*)(swh + (2 * tid) * 24)          = a0;
      *(uint4*)(swh + (2 * tid) * 24 + 8)      = a1;
      *(uint4*)(swh + (2 * tid + 1) * 24)      = a2;
      *(uint4*)(swh + (2 * tid + 1) * 24 + 8)  = a3;
      *(uint4*)(swl + (2 * tid) * 24)          = c0;
      *(uint4*)(swl + (2 * tid) * 24 + 8)      = c1;
      *(uint4*)(swl + (2 * tid + 1) * 24)      = c2;
      *(uint4*)(swl + (2 * tid + 1) * 24 + 8)  = c3;
    }
    __syncthreads();
    // fragments + MFMA. A: m=lane&31, k=(lane>>5)*8+j. B: n=lane&31, same k.
    short8 ah[2], al[2];
#pragma unroll
    for (int mt = 0; mt < 2; ++mt) {
      ah[mt] = *(const short8*)(sxh + (mt * 32 + l31) * 24 + h5 * 8);
      al[mt] = *(const short8*)(sxl + (mt * 32 + l31) * 24 + h5 * 8);
    }
#pragma unroll
    for (int nt = 0; nt < 4; ++nt) {
      const int n = wave * 128 + nt * 32 + l31;
      short8 bh = *(const short8*)(swh + n * 24 + h5 * 8);
      short8 bl = *(const short8*)(swl + n * 24 + h5 * 8);
#pragma unroll
      for (int mt = 0; mt < 2; ++mt) {
        acc[mt][nt] = __builtin_amdgcn_mfma_f32_32x32x16_bf16(ah[mt], bh, acc[mt][nt], 0, 0, 0);
        acc[mt][nt] = __builtin_amdgcn_mfma_f32_32x32x16_bf16(al[mt], bh, acc[mt][nt], 0, 0, 0);
        acc[mt][nt] = __builtin_amdgcn_mfma_f32_32x32x16_bf16(ah[mt], bl, acc[mt][nt], 0, 0, 0);
      }
    }
  }

  // epilogue: relu(h + b1)*W2, reduce 512 cols -> ylin per token.
  // C/D layout (verified m74/m101): col=lane&31, row=(r&3)+8*(r>>2)+4*(lane>>5)
  float b1v[4], w2v[4];
#pragma unroll
  for (int nt = 0; nt < 4; ++nt) {
    const int n = wave * 128 + nt * 32 + l31;
    b1v[nt] = b1[n];
    w2v[nt] = W2[n];
  }
  __syncthreads();                 // done with staging LDS; reuse as red
  float* red = (float*)smem;       // [4][64][33]
#pragma unroll
  for (int mt = 0; mt < 2; ++mt) {
    float p[16];
#pragma unroll
    for (int r = 0; r < 16; ++r) p[r] = 0.f;
#pragma unroll
    for (int nt = 0; nt < 4; ++nt)
#pragma unroll
      for (int r = 0; r < 16; ++r)
        p[r] += fmaxf(acc[mt][nt][r] + b1v[nt], 0.f) * w2v[nt];
#pragma unroll
    for (int r = 0; r < 16; ++r) {
      int row = (r & 3) + 8 * (r >> 2) + 4 * h5;
      red[(wave * 64 + mt * 32 + row) * 33 + l31] = p[r];
    }
  }
  __syncthreads();
  if (tid < 64) {
    float s = 0.f;
#pragma unroll
    for (int w = 0; w < 4; ++w)
      for (int c = 0; c < 32; ++c) s += red[(w * 64 + tid) * 33 + c];
    ylin[tok0 + tid] = s;
  }
}

// ---------------------------------------------------------------------------
// K2: per batch row -- squash, zero pads, row max -> adjust, threshold mask,
// stable block prefix-scan -> src_of_dest mapping, new_len, v_pad output.
// ---------------------------------------------------------------------------
__global__ __launch_bounds__(256)
void k2_row(const float* __restrict__ ylin, const int* __restrict__ pad,
            const float* __restrict__ b2, float* __restrict__ yfin,
            int* __restrict__ src_of_dest, int* __restrict__ new_len,
            float* __restrict__ vpad_out) {
  __shared__ float sred[256];
  __shared__ int scnt[256];
  const int b = blockIdx.x;
  const int tid = threadIdx.x;
  const int base = b * NS;
  const int s0 = tid * 16;

  float yv[16];
  unsigned pm = 0;
  float lmax = 0.f;
  const float b2v = b2[0];
#pragma unroll
  for (int i = 0; i < 16; ++i) {
    int s = s0 + i;
    float yl = ylin[base + s] + b2v;
    float y = (1.f + tanhf(10.f * yl)) * 0.5f;
    if (pad[base + s]) { y = 0.f; pm |= (1u << i); }
    yv[i] = y;
    lmax = fmaxf(lmax, y);
  }
  sred[tid] = lmax;
  __syncthreads();
  for (int o = 128; o > 0; o >>= 1) {
    if (tid < o) sred[tid] = fmaxf(sred[tid], sred[tid + o]);
    __syncthreads();
  }
  const float adj = fmaxf(EPSV + THRESH - sred[0], 0.f);

  int cnt = 0;
  unsigned km = 0;
#pragma unroll
  for (int i = 0; i < 16; ++i) {
    float yf = yv[i] + adj;
    yv[i] = yf;
    bool keep = (yf > THRESH) && !((pm >> i) & 1u);
    if (keep) { km |= (1u << i); ++cnt; }
  }
  scnt[tid] = cnt;
  __syncthreads();
  for (int o = 1; o < 256; o <<= 1) {
    int add = (tid >= o) ? scnt[tid - o] : 0;
    __syncthreads();
    scnt[tid] += add;
    __syncthreads();
  }
  const int total = scnt[255];
  int off = scnt[tid] - cnt;
#pragma unroll
  for (int i = 0; i < 16; ++i) {
    int s = s0 + i;
    yfin[base + s] = yv[i];
    if ((km >> i) & 1u) { src_of_dest[base + off] = s; ++off; }
    vpad_out[base + s] = (s >= total) ? 1.f : 0.f;
  }
  if (tid == 0) new_len[b] = total;
}

// ---------------------------------------------------------------------------
// K3: one block per output slot (b, dest): v = x[src]*y_final[src] or zeros.
// ---------------------------------------------------------------------------
__global__ __launch_bounds__(256)
void k3_gather(const float* __restrict__ x, const float* __restrict__ yfin,
               const int* __restrict__ src_of_dest, const int* __restrict__ new_len,
               float* __restrict__ v) {
  const int slot = blockIdx.x;
  const int b = slot >> 12;
  const int dest = slot & (NS - 1);
  const int tid = threadIdx.x;
  float4* vo = (float4*)(v + (size_t)slot * ND);
  if (dest < new_len[b]) {
    const int src = src_of_dest[slot];
    const float g = yfin[b * NS + src];
    const float4* xi = (const float4*)(x + ((size_t)b * NS + src) * ND);
    float4 xv = xi[tid];
    vo[tid] = make_float4(xv.x * g, xv.y * g, xv.z * g, xv.w * g);
  } else {
    vo[tid] = make_float4(0.f, 0.f, 0.f, 0.f);
  }
}

extern "C" void kernel_launch(void* const* d_in, const int* in_sizes, int n_in,
                              void* d_out, int out_size, void* d_ws, size_t ws_size,
                              hipStream_t stream) {
  const float* x   = (const float*)d_in[0];
  const int*   pad = (const int*)d_in[1];
  const float* W1  = (const float*)d_in[2];
  const float* b1  = (const float*)d_in[3];
  const float* W2  = (const float*)d_in[4];
  const float* b2  = (const float*)d_in[5];

  float* v    = (float*)d_out;                 // [8,4096,1024]
  float* vpad = v + (size_t)NTOK * ND;         // [8,4096]

  // split-W scratch lives inside d_out's v region (k1 reads it; k3 later
  // overwrites every v element, so it's free scratch with no race).
  unsigned short* WtHi = (unsigned short*)(v + 24000000);  // 1 MB
  unsigned short* WtLo = (unsigned short*)(v + 24400000);  // 1 MB

  // d_ws: small fp32/int scratch (~384 KB, proven fit in round 1)
  float* ylin = (float*)d_ws;                  // NTOK
  float* yfin = ylin + NTOK;                   // NTOK
  int* src    = (int*)(yfin + NTOK);           // NTOK
  int* nlen   = src + NTOK;                    // NB

  k0_prep<<<512, 256, 0, stream>>>(W1, WtHi, WtLo);
  k1_gemm<<<NTOK / BM, 256, 0, stream>>>(x, WtHi, WtLo, b1, W2, ylin);
  k2_row<<<NB, 256, 0, stream>>>(ylin, pad, b2, yfin, src, nlen, vpad);
  k3_gather<<<NTOK, 256, 0, stream>>>(x, yfin, src, nlen, v);
}

// Round 3
// 321.948 us; speedup vs baseline: 1.9670x; 1.0454x over previous
//
#include <hip/hip_runtime.h>
#include <math.h>

// SoftGate: gate-MLP (split-bf16 MFMA, B-frags direct from L2) -> threshold
// -> stable compaction.
#define NB 8
#define NS 4096
#define ND 1024      // K (feature dim)
#define NDH 512      // N (hidden dim)
#define NTOK (NB*NS) // M = 32768
#define THRESH 0.1f
#define EPSV 1e-5f

using short8   = __attribute__((ext_vector_type(8)))  short;
using floatx16 = __attribute__((ext_vector_type(16))) float;

__device__ __forceinline__ unsigned short f32_to_bf16_rne(float f) {
  union { float f; unsigned u; } v; v.f = f;
  unsigned r = v.u + 0x7fffu + ((v.u >> 16) & 1u);
  return (unsigned short)(r >> 16);
}
__device__ __forceinline__ float bf16_to_f32(unsigned short h) {
  union { unsigned u; float f; } v; v.u = ((unsigned)h) << 16;
  return v.f;
}

// ---------------------------------------------------------------------------
// K0: repack W1 into MFMA-B-fragment order, bf16 hi/lo interleaved by chunk:
//   chunk(n32,k16) = 64 lanes x 16 B; lane l holds n = n32*32+(l&31),
//   k = k16*16+(l>>5)*8+j (j=0..7).  addr = ((n32*64+k16)*2 + s)*512 + l*8.
// A wave's B-fragment load is then ONE coalesced global_load_dwordx4 (1 KB).
// Also zero-inits rowmax for k2a's atomicMax.
// ---------------------------------------------------------------------------
__global__ __launch_bounds__(256)
void k0_prep(const float* __restrict__ W1, unsigned short* __restrict__ Wf,
             unsigned int* __restrict__ rowmax) {
  __shared__ float sw[16][513];
  const int t = threadIdx.x;
  const int k16 = blockIdx.x;                // 0..63
  if (k16 == 0 && t < NB) rowmax[t] = 0u;
#pragma unroll
  for (int i = 0; i < 8; ++i) {
    int flat = i * 256 + t;                  // 2048 float4s
    int r = flat >> 7, c4 = (flat & 127) << 2;
    *(float4*)&sw[r][c4] = *(const float4*)(W1 + (size_t)(k16 * 16 + r) * NDH + c4);
  }
  __syncthreads();
#pragma unroll
  for (int q = 0; q < 4; ++q) {
    int ss = q * 256 + t;                    // 1024 lane-slots
    int n32 = ss >> 6, lane = ss & 63;
    int n = n32 * 32 + (lane & 31);
    int kb = (lane >> 5) * 8;
    unsigned hi2[4], lo2[4];
#pragma unroll
    for (int j = 0; j < 4; ++j) {
      float w0 = sw[kb + 2 * j][n], w1 = sw[kb + 2 * j + 1][n];
      unsigned short h0 = f32_to_bf16_rne(w0), h1 = f32_to_bf16_rne(w1);
      unsigned short l0 = f32_to_bf16_rne(w0 - bf16_to_f32(h0));
      unsigned short l1 = f32_to_bf16_rne(w1 - bf16_to_f32(h1));
      hi2[j] = (unsigned)h0 | ((unsigned)h1 << 16);
      lo2[j] = (unsigned)l0 | ((unsigned)l1 << 16);
    }
    size_t cb = ((size_t)(n32 * 64 + k16) * 2) * 512 + (size_t)lane * 8;
    *(uint4*)(Wf + cb)       = make_uint4(hi2[0], hi2[1], hi2[2], hi2[3]);
    *(uint4*)(Wf + cb + 512) = make_uint4(lo2[0], lo2[1], lo2[2], lo2[3]);
  }
}

// ---------------------------------------------------------------------------
// K1: ylin[token] = sum_n relu((x·W1)[n]+b1[n])*W2[n] via 3-term split-bf16
// MFMA (hi·hi + lo·hi + hi·lo), fp32 accumulate.
// BM=64 tokens x full N=512, BK=32.  B-fragments stream straight from
// global/L2 (pre-swizzled by k0) -> registers; only x is staged in LDS
// (double-buffered, ONE barrier per K-iter).  Wave w owns cols [128w,128w+128).
// ---------------------------------------------------------------------------
__global__ __launch_bounds__(256, 2)
void k1_gemm(const float* __restrict__ x, const unsigned short* __restrict__ Wf,
             const float* __restrict__ b1, const float* __restrict__ W2,
             float* __restrict__ ylin) {
  __shared__ __align__(16) unsigned short sx[2][2][64 * 40];  // [buf][hi/lo][m*40+k]
  __shared__ float red[4][64];

  const int tid = threadIdx.x;
  const int wave = tid >> 6, lane = tid & 63;
  const int l31 = lane & 31, h5 = lane >> 5;
  const int tok0 = blockIdx.x * 64;

  floatx16 acc[2][4];
#pragma unroll
  for (int mt = 0; mt < 2; ++mt)
#pragma unroll
    for (int nt = 0; nt < 4; ++nt)
#pragma unroll
      for (int r = 0; r < 16; ++r) acc[mt][nt][r] = 0.f;

  const int sm = tid >> 2;            // staging row 0..63
  const int sk = (tid & 3) * 8;       // staging k-offset {0,8,16,24}
  const float* xrow = x + (size_t)(tok0 + sm) * ND + sk;

  const unsigned short* wb[4];
#pragma unroll
  for (int nt = 0; nt < 4; ++nt)
    wb[nt] = Wf + (((size_t)(wave * 4 + nt) * 64) * 2) * 512 + (size_t)lane * 8;

  for (int it = 0; it < 32; ++it) {
    const int p = it & 1;
    // B fragments: global -> regs (coalesced 1 KB per wave per load).
    // These drain at the barrier below, overlapping the x-stage work.
    short8 bh[4][2], bl[4][2];
#pragma unroll
    for (int nt = 0; nt < 4; ++nt)
#pragma unroll
      for (int kh = 0; kh < 2; ++kh) {
        const unsigned short* q = wb[nt] + ((size_t)(2 * it + kh) * 2) * 512;
        bh[nt][kh] = *(const short8*)(q);
        bl[nt][kh] = *(const short8*)(q + 512);
      }
    // x stage: 64x32 fp32 -> bf16 hi/lo split, double-buffered LDS
    {
      const float* xp = xrow + it * 32;
      float4 xa = *(const float4*)xp;
      float4 xb = *(const float4*)(xp + 4);
      float v8[8] = {xa.x, xa.y, xa.z, xa.w, xb.x, xb.y, xb.z, xb.w};
      unsigned hp[4], lp[4];
#pragma unroll
      for (int j = 0; j < 4; ++j) {
        unsigned short h0 = f32_to_bf16_rne(v8[2 * j]);
        unsigned short h1 = f32_to_bf16_rne(v8[2 * j + 1]);
        unsigned short l0 = f32_to_bf16_rne(v8[2 * j] - bf16_to_f32(h0));
        unsigned short l1 = f32_to_bf16_rne(v8[2 * j + 1] - bf16_to_f32(h1));
        hp[j] = (unsigned)h0 | ((unsigned)h1 << 16);
        lp[j] = (unsigned)l0 | ((unsigned)l1 << 16);
      }
      *(uint4*)&sx[p][0][sm * 40 + sk] = make_uint4(hp[0], hp[1], hp[2], hp[3]);
      *(uint4*)&sx[p][1][sm * 40 + sk] = make_uint4(lp[0], lp[1], lp[2], lp[3]);
    }
    __syncthreads();   // single barrier/iter (dbuf removes the second one)
    // A fragments: lane holds x[tok=mt*32+l31][k = kh*16 + h5*8 + j]
    short8 ah[2][2], al[2][2];
#pragma unroll
    for (int mt = 0; mt < 2; ++mt)
#pragma unroll
      for (int kh = 0; kh < 2; ++kh) {
        ah[mt][kh] = *(const short8*)&sx[p][0][(mt * 32 + l31) * 40 + kh * 16 + h5 * 8];
        al[mt][kh] = *(const short8*)&sx[p][1][(mt * 32 + l31) * 40 + kh * 16 + h5 * 8];
      }
#pragma unroll
    for (int kh = 0; kh < 2; ++kh)
#pragma unroll
      for (int nt = 0; nt < 4; ++nt)
#pragma unroll
        for (int mt = 0; mt < 2; ++mt) {
          acc[mt][nt] = __builtin_amdgcn_mfma_f32_32x32x16_bf16(ah[mt][kh], bh[nt][kh], acc[mt][nt], 0, 0, 0);
          acc[mt][nt] = __builtin_amdgcn_mfma_f32_32x32x16_bf16(al[mt][kh], bh[nt][kh], acc[mt][nt], 0, 0, 0);
          acc[mt][nt] = __builtin_amdgcn_mfma_f32_32x32x16_bf16(ah[mt][kh], bl[nt][kh], acc[mt][nt], 0, 0, 0);
        }
  }

  // epilogue: relu(h+b1)*W2, shfl-reduce the 32 col-lanes, tiny LDS combine.
  // C/D layout (m74/m101): col=lane&31, row=(r&3)+8*(r>>2)+4*(lane>>5)
  float b1v[4], w2v[4];
#pragma unroll
  for (int nt = 0; nt < 4; ++nt) {
    const int n = wave * 128 + nt * 32 + l31;
    b1v[nt] = b1[n];
    w2v[nt] = W2[n];
  }
#pragma unroll
  for (int mt = 0; mt < 2; ++mt) {
    float pr[16];
#pragma unroll
    for (int r = 0; r < 16; ++r) pr[r] = 0.f;
#pragma unroll
    for (int nt = 0; nt < 4; ++nt)
#pragma unroll
      for (int r = 0; r < 16; ++r)
        pr[r] += fmaxf(acc[mt][nt][r] + b1v[nt], 0.f) * w2v[nt];
#pragma unroll
    for (int m = 1; m <= 16; m <<= 1)
#pragma unroll
      for (int r = 0; r < 16; ++r) pr[r] += __shfl_xor(pr[r], m, 64);
    if (l31 == 0) {
#pragma unroll
      for (int r = 0; r < 16; ++r) {
        int row = (r & 3) + 8 * (r >> 2) + 4 * h5;
        red[wave][mt * 32 + row] = pr[r];
      }
    }
  }
  __syncthreads();
  if (tid < 64)
    ylin[tok0 + tid] = red[0][tid] + red[1][tid] + red[2][tid] + red[3][tid];
}

// ---------------------------------------------------------------------------
// K2a: squash (tanh kept for bit-compat with np ref), zero pads, exact
// per-row max via atomicMax on float bits (y>=0 -> monotone; max is exact so
// any atomic order is deterministic).  128 blocks, 1 token/thread.
// ---------------------------------------------------------------------------
__global__ __launch_bounds__(256)
void k2a(const float* __restrict__ ylin, const int* __restrict__ pad,
         const float* __restrict__ b2, float* __restrict__ ysq,
         unsigned int* __restrict__ rowmax) {
  __shared__ float wm[4];
  const int t = blockIdx.x * 256 + threadIdx.x;
  float yl = ylin[t] + b2[0];
  float y = (1.f + tanhf(10.f * yl)) * 0.5f;
  if (pad[t]) y = 0.f;
  ysq[t] = y;
  float m = y;
#pragma unroll
  for (int s = 32; s >= 1; s >>= 1) m = fmaxf(m, __shfl_xor(m, s, 64));
  if ((threadIdx.x & 63) == 0) wm[threadIdx.x >> 6] = m;
  __syncthreads();
  if (threadIdx.x == 0) {
    float bm = fmaxf(fmaxf(wm[0], wm[1]), fmaxf(wm[2], wm[3]));
    atomicMax(rowmax + (t >> 12), __float_as_uint(bm));
  }
}

// ---------------------------------------------------------------------------
// K2b: per row -- adjust, threshold mask, stable prefix-scan -> compaction
// map, new_len, v_pad.  One block per row.
// ---------------------------------------------------------------------------
__global__ __launch_bounds__(256)
void k2b(const float* __restrict__ ysq, const int* __restrict__ pad,
         const unsigned int* __restrict__ rowmax, float* __restrict__ yfin,
         int* __restrict__ src_of_dest, int* __restrict__ new_len,
         float* __restrict__ vpad_out) {
  __shared__ int scnt[256];
  const int b = blockIdx.x, tid = threadIdx.x;
  const int base = b * NS, s0 = tid * 16;
  const float adj = fmaxf(EPSV + THRESH - __uint_as_float(rowmax[b]), 0.f);

  float yv[16];
  unsigned km = 0;
  int cnt = 0;
#pragma unroll
  for (int i = 0; i < 16; ++i) {
    int s = s0 + i;
    float yf = ysq[base + s] + adj;
    yv[i] = yf;
    bool keep = (yf > THRESH) && !pad[base + s];
    if (keep) { km |= (1u << i); ++cnt; }
  }
  scnt[tid] = cnt;
  __syncthreads();
  for (int o = 1; o < 256; o <<= 1) {
    int add = (tid >= o) ? scnt[tid - o] : 0;
    __syncthreads();
    scnt[tid] += add;
    __syncthreads();
  }
  const int total = scnt[255];
  int off = scnt[tid] - cnt;
#pragma unroll
  for (int i = 0; i < 16; ++i) {
    int s = s0 + i;
    yfin[base + s] = yv[i];
    if ((km >> i) & 1u) { src_of_dest[base + off] = s; ++off; }
    vpad_out[base + s] = (s >= total) ? 1.f : 0.f;
  }
  if (tid == 0) new_len[b] = total;
}

// ---------------------------------------------------------------------------
// K3: 4 output slots per block: v = x[src]*y_final[src] or zeros.
// ---------------------------------------------------------------------------
__global__ __launch_bounds__(256)
void k3_gather(const float* __restrict__ x, const float* __restrict__ yfin,
               const int* __restrict__ src_of_dest, const int* __restrict__ new_len,
               float* __restrict__ v) {
  const int slot0 = blockIdx.x * 4;
  const int b = slot0 >> 12;            // 4096 slots per row, 4 | 4096
  const int nl = new_len[b];
  const int tid = threadIdx.x;
#pragma unroll
  for (int i = 0; i < 4; ++i) {
    const int slot = slot0 + i;
    const int dest = slot & (NS - 1);
    float4* vo = (float4*)(v + (size_t)slot * ND);
    if (dest < nl) {
      const int src = src_of_dest[slot];
      const float g = yfin[b * NS + src];
      const float4* xi = (const float4*)(x + ((size_t)b * NS + src) * ND);
      float4 xv = xi[tid];
      vo[tid] = make_float4(xv.x * g, xv.y * g, xv.z * g, xv.w * g);
    } else {
      vo[tid] = make_float4(0.f, 0.f, 0.f, 0.f);
    }
  }
}

extern "C" void kernel_launch(void* const* d_in, const int* in_sizes, int n_in,
                              void* d_out, int out_size, void* d_ws, size_t ws_size,
                              hipStream_t stream) {
  const float* x   = (const float*)d_in[0];
  const int*   pad = (const int*)d_in[1];
  const float* W1  = (const float*)d_in[2];
  const float* b1  = (const float*)d_in[3];
  const float* W2  = (const float*)d_in[4];
  const float* b2  = (const float*)d_in[5];

  float* v    = (float*)d_out;                 // [8,4096,1024]
  float* vpad = v + (size_t)NTOK * ND;         // [8,4096]

  // Scratch inside d_out's v region: k3 rewrites every v element afterwards,
  // and all kernels are out-of-place (rocprof replay in dispatch order safe).
  unsigned short* Wf = (unsigned short*)(v + 24000000);  // 2 MB fragment-packed W
  float* ysq = v + 26000000;                             // 128 KB squashed gate

  // d_ws (~384 KB): ylin, yfin, src map, new_len, rowmax
  float* ylin = (float*)d_ws;
  float* yfin = ylin + NTOK;
  int* src    = (int*)(yfin + NTOK);
  int* nlen   = src + NTOK;
  unsigned int* rowmax = (unsigned int*)(nlen + NB);

  k0_prep<<<64, 256, 0, stream>>>(W1, Wf, rowmax);
  k1_gemm<<<NTOK / 64, 256, 0, stream>>>(x, Wf, b1, W2, ylin);
  k2a<<<NTOK / 256, 256, 0, stream>>>(ylin, pad, b2, ysq, rowmax);
  k2b<<<NB, 256, 0, stream>>>(ysq, pad, rowmax, yfin, src, nlen, vpad);
  k3_gather<<<NTOK / 4, 256, 0, stream>>>(x, yfin, src, nlen, v);
}